// Round 16
// baseline (149.037 us; speedup 1.0000x reference)
//
#include <hip/hip_runtime.h>

#define CHUNK 1024  // points per block-pass (streamed via SGPRs)
#define GRP   32    // group-tracking granularity
#define QB    4     // fallback: queries per block

// ---------------------------------------------------------------------------
// FUSED single-kernel design (round-14 measurement: T_main ~= 10-12 us, but
// ~20 us of init/gather dispatches + gaps -> fuse everything).
//
// Grid = nchunk x nqg blocks. Block (ck, qg): 256 threads = 4 waves, one
// query per lane (q = qg*256 + wv*64 + lane), scans chunk ck via wave-uniform
// s_load (readfirstlane makes wv provably uniform). Distance-only min
// (v_sub + v_min3 with |abs| modifiers, 2 chains), GRP=32 group tracking:
// grp = last group that strictly lowered the min == FIRST group containing
// the final min (min only strictly decreases; ties never update). Epilogue
// rescans the winning 32 points descending, keeping the smallest index whose
// recomputed distance is bit-identical (same IEEE ops -> same bits).
//
// Merge: coalesced u64 partial stores part[ck][q] (no init needed), then
// __threadfence + atomicAdd ticket on counters[qg] (zeroed every call by a
// hipMemsetAsync node in the captured graph -> no poison dependence). The
// LAST-arriving block of each qg reduces its 256 queries over all nchunk
// partials (coalesced) and gathers acc -> out. Deterministic: reduce only
// runs after every chunk-block of that qg has stored+fenced; u64 key
// (dist_bits<<32 | idx) preserves numpy first-index tie-break exactly
// (dist >= 0 -> f32 bits monotone; idx ascending).
// ---------------------------------------------------------------------------
__global__ __launch_bounds__(256, 8)
void nn_fused_kernel(const float* __restrict__ x,
                     const float* __restrict__ pts,
                     const float* __restrict__ acc,
                     float* __restrict__ out,
                     unsigned long long* __restrict__ part, // [nchunk][B]
                     unsigned int* __restrict__ counters,   // [nqg], zeroed
                     int B, int nchunk, int qg_shift)
{
    const int tid  = threadIdx.x;
    const int lane = tid & 63;
    // load-bearing: makes the wave id (hence nothing per-lane leaks into the
    // chunk addressing) provably uniform -> s_load codegen
    const int wv   = __builtin_amdgcn_readfirstlane(tid >> 6);
    const int qg   = blockIdx.x & ((1 << qg_shift) - 1);
    const int ck   = blockIdx.x >> qg_shift;

    const int q = (qg << 8) + (wv << 6) + lane;
    const float xq = x[q];

    const float* __restrict__ pc = pts + (size_t)(unsigned)ck * CHUNK;

    const float inf = __builtin_inff();
    float bdA = inf, bdB = inf, prev = inf;
    int grp = 0;

    #pragma unroll 2
    for (int g = 0; g < CHUNK / GRP; ++g) {
        #pragma unroll
        for (int t = 0; t < GRP / 4; ++t) {
            // wave-uniform scalar loads (SMEM pipe), SGPR operands to VALU
            float p0 = pc[g * GRP + 4 * t + 0];
            float p1 = pc[g * GRP + 4 * t + 1];
            float p2 = pc[g * GRP + 4 * t + 2];
            float p3 = pc[g * GRP + 4 * t + 3];
            bdA = fminf(fminf(fabsf(p0 - xq), fabsf(p1 - xq)), bdA);
            bdB = fminf(fminf(fabsf(p2 - xq), fabsf(p3 - xq)), bdB);
        }
        float cur = fminf(bdA, bdB);
        grp  = (cur < prev) ? g : grp;       // ~3 VALU per 32 points
        prev = cur;
    }

    const float bd = prev;

    // Epilogue: first index in winning group with dist bit-equal to bd.
    // Per-lane float4 gathers (divergent grp), once per 1024-pt chunk.
    const float4* __restrict__ pg =
        reinterpret_cast<const float4*>(pc + grp * GRP);
    int bi = 0;
    #pragma unroll
    for (int t = GRP / 4 - 1; t >= 0; --t) {   // descending -> first wins
        float4 v = pg[t];
        bi = (fabsf(v.w - xq) == bd) ? 4 * t + 3 : bi;
        bi = (fabsf(v.z - xq) == bd) ? 4 * t + 2 : bi;
        bi = (fabsf(v.y - xq) == bd) ? 4 * t + 1 : bi;
        bi = (fabsf(v.x - xq) == bd) ? 4 * t + 0 : bi;
    }

    const unsigned gidx = (unsigned)(ck * CHUNK + grp * GRP + bi);
    const unsigned long long key =
        ((unsigned long long)__float_as_uint(bd) << 32) | gidx;

    part[(size_t)ck * B + q] = key;          // coalesced 8B store

    // ---- last-block-per-qg reduction ----
    __threadfence();                         // release our stores (device scope)
    __shared__ int last_flag;
    if (tid == 0) {
        unsigned int old = atomicAdd(&counters[qg], 1u);
        last_flag = (old == (unsigned)(nchunk - 1)) ? 1 : 0;
    }
    __syncthreads();
    if (last_flag) {
        __threadfence();                     // acquire side
        const int qq = (qg << 8) + tid;      // one query per thread
        unsigned long long bk = ~0ULL;
        #pragma unroll 8
        for (int c = 0; c < nchunk; ++c) {
            unsigned long long k = part[(size_t)c * B + qq]; // coalesced
            bk = k < bk ? k : bk;
        }
        out[qq] = acc[(unsigned)(bk & 0xffffffffULL)];
    }
}

// ---------------------------------------------------------------------------
// Fallback (round-1 kernel): one query per wave, vector loads. Generic.
// ---------------------------------------------------------------------------
__global__ __launch_bounds__(256, 4)
void nn_kernel(const float* __restrict__ x,
               const float* __restrict__ pts,
               const float* __restrict__ acc,
               float* __restrict__ out,
               int B, int N) {
    const int lane = threadIdx.x & 63;
    const int wave = threadIdx.x >> 6;
    const int q    = blockIdx.x * QB + wave;
    if (q >= B) return;

    const float xq = x[q];
    const int G = N >> 2;
    const int J = G >> 6;

    float bd0 = __builtin_inff(), bd1 = __builtin_inff(),
          bd2 = __builtin_inff(), bd3 = __builtin_inff();
    int   bj0 = 0, bj1 = 0, bj2 = 0, bj3 = 0;

    const float4* __restrict__ p4 = reinterpret_cast<const float4*>(pts);

    #pragma unroll 4
    for (int j = 0; j < J; ++j) {
        float4 v = p4[lane + 64 * j];
        float d0 = fabsf(v.x - xq);
        float d1 = fabsf(v.y - xq);
        float d2 = fabsf(v.z - xq);
        float d3 = fabsf(v.w - xq);
        if (d0 < bd0) { bd0 = d0; bj0 = j; }
        if (d1 < bd1) { bd1 = d1; bj1 = j; }
        if (d2 < bd2) { bd2 = d2; bj2 = j; }
        if (d3 < bd3) { bd3 = d3; bj3 = j; }
    }

    unsigned long long key;
    {
        unsigned i0 = (unsigned)(4 * (lane + 64 * bj0) + 0);
        unsigned i1 = (unsigned)(4 * (lane + 64 * bj1) + 1);
        unsigned i2 = (unsigned)(4 * (lane + 64 * bj2) + 2);
        unsigned i3 = (unsigned)(4 * (lane + 64 * bj3) + 3);
        unsigned long long k0 = ((unsigned long long)__float_as_uint(bd0) << 32) | i0;
        unsigned long long k1 = ((unsigned long long)__float_as_uint(bd1) << 32) | i1;
        unsigned long long k2 = ((unsigned long long)__float_as_uint(bd2) << 32) | i2;
        unsigned long long k3 = ((unsigned long long)__float_as_uint(bd3) << 32) | i3;
        key = k0 < k1 ? k0 : k1;
        unsigned long long k23 = k2 < k3 ? k2 : k3;
        key = key < k23 ? key : k23;
    }

    for (int i = J * 256 + lane; i < N; i += 64) {
        float d = fabsf(pts[i] - xq);
        unsigned long long k = ((unsigned long long)__float_as_uint(d) << 32) | (unsigned)i;
        key = key < k ? key : k;
    }

    #pragma unroll
    for (int off = 1; off < 64; off <<= 1) {
        unsigned long long o = __shfl_xor(key, off, 64);
        key = key < o ? key : o;
    }

    if (lane == 0) {
        out[q] = acc[(unsigned)(key & 0xffffffffULL)];
    }
}

extern "C" void kernel_launch(void* const* d_in, const int* in_sizes, int n_in,
                              void* d_out, int out_size, void* d_ws, size_t ws_size,
                              hipStream_t stream) {
    const float* x   = (const float*)d_in[0];
    const float* pts = (const float*)d_in[1];
    const float* acc = (const float*)d_in[2];
    float* out = (float*)d_out;
    const int B = in_sizes[0];
    const int N = in_sizes[1];

    const int nchunk = N / CHUNK;
    const int nqg    = B >> 8;                   // query groups of 256
    const bool pow2  = (nqg > 0) && ((nqg & (nqg - 1)) == 0);

    const size_t part_bytes = (size_t)nchunk * (size_t)B * 8;
    const size_t need       = part_bytes + 256 + (size_t)nqg * 4;
    const bool fast = pow2 && (B % 256 == 0) && (N % CHUNK == 0) &&
                      d_ws != nullptr && ws_size >= need;

    if (fast) {
        int qg_shift = 0;
        while ((1 << qg_shift) < nqg) ++qg_shift;

        unsigned long long* part = (unsigned long long*)d_ws;
        unsigned int* counters =
            (unsigned int*)((char*)d_ws + ((part_bytes + 255) & ~(size_t)255));

        // Zero the arrival counters INSIDE the captured graph (memset node),
        // so every replay starts from 0 regardless of ws poisoning.
        hipMemsetAsync(counters, 0, (size_t)nqg * 4, stream);
        hipLaunchKernelGGL(nn_fused_kernel, dim3(nchunk * nqg), dim3(256), 0,
                           stream, x, pts, acc, out, part, counters,
                           B, nchunk, qg_shift);
    } else {
        const int blocks = (B + QB - 1) / QB;
        hipLaunchKernelGGL(nn_kernel, dim3(blocks), dim3(256), 0, stream,
                           x, pts, acc, out, B, N);
    }
}